// Round 9
// baseline (535.358 us; speedup 1.0000x reference)
//
#include <hip/hip_runtime.h>
#include <hip/hip_bf16.h>

#define Tt   16384
#define Dd   1024
#define Ee   8
#define CAP  2048
#define DFFf 4096

typedef __attribute__((ext_vector_type(8))) short bf16x8;
typedef __attribute__((ext_vector_type(4))) float f32x4;

__device__ __forceinline__ unsigned short f2bf(float f) {
  union { float f; unsigned u; } v; v.f = f;
  unsigned r = (v.u + 0x7FFFu + ((v.u >> 16) & 1u)) >> 16;
  return (unsigned short)r;
}

__device__ __forceinline__ float gelu_tanh(float x) {
  float z = 0.7978845608028654f * (x + 0.044715f * x * x * x);
  float az = fabsf(z);
  float t = __expf(-2.0f * az);
  float th = (1.0f - t) / (1.0f + t);
  th = (z < 0.0f) ? -th : th;
  return 0.5f * x * (1.0f + th);
}

__device__ __forceinline__ void gld16(const void* g, void* l) {
  __builtin_amdgcn_global_load_lds(
      (const __attribute__((address_space(1))) void*)g,
      (__attribute__((address_space(3))) void*)l,
      16, 0, 0);
}

template <int IMM>
__device__ __forceinline__ bf16x8 dsr(unsigned a) {
  bf16x8 r;
  asm volatile("ds_read_b128 %0, %1 offset:%c2" : "=v"(r) : "v"(a), "i"(IMM));
  return r;
}
#define LGKM(N) asm volatile("s_waitcnt lgkmcnt(" #N ")" ::: "memory")
#define VMCNT(N) asm volatile("s_waitcnt vmcnt(" #N ")" ::: "memory")

// ---------------- gating: logits fp32, softmax, argmax ----------------
__global__ __launch_bounds__(256) void gating_kernel(
    const float* __restrict__ x, const float* __restrict__ wg,
    int* __restrict__ idx, float* __restrict__ gate, float* __restrict__ meP) {
  int tid = threadIdx.x, lane = tid & 63, w = tid >> 6;
  int t = blockIdx.x * 4 + w;
  const float* xr = x + (size_t)t * Dd;
  float p[8];
#pragma unroll
  for (int e2 = 0; e2 < 8; ++e2) p[e2] = 0.f;
#pragma unroll
  for (int i = 0; i < 16; ++i) {
    int j = lane + (i << 6);
    float xv = xr[j];
    const float4* wr = (const float4*)(wg + j * 8);
    float4 a = wr[0], b = wr[1];
    p[0] += xv * a.x; p[1] += xv * a.y; p[2] += xv * a.z; p[3] += xv * a.w;
    p[4] += xv * b.x; p[5] += xv * b.y; p[6] += xv * b.z; p[7] += xv * b.w;
  }
#pragma unroll
  for (int off = 32; off > 0; off >>= 1)
#pragma unroll
    for (int e2 = 0; e2 < 8; ++e2) p[e2] += __shfl_xor(p[e2], off);
  __shared__ float smG[4][8];
  if (lane == 0) {
    float mx = p[0]; int am = 0;
#pragma unroll
    for (int e2 = 1; e2 < 8; ++e2) if (p[e2] > mx) { mx = p[e2]; am = e2; }
    float s = 0.f, g2[8];
#pragma unroll
    for (int e2 = 0; e2 < 8; ++e2) { g2[e2] = __expf(p[e2] - mx); s += g2[e2]; }
    float inv = 1.f / s;
    idx[t] = am;
    gate[t] = g2[am] * inv;
#pragma unroll
    for (int e2 = 0; e2 < 8; ++e2) smG[w][e2] = g2[e2] * inv;
  }
  __syncthreads();
  if (tid < 8)
    meP[blockIdx.x * 8 + tid] = smG[0][tid] + smG[1][tid] + smG[2][tid] + smG[3][tid];
}

// ------------- scan: per-expert cumulative position + l_aux -------------
__global__ __launch_bounds__(512) void scan_kernel(
    const int* __restrict__ idx, int* __restrict__ pos, int* __restrict__ smap,
    const float* __restrict__ meP, int nblkG, float* __restrict__ laux_out) {
  int tid = threadIdx.x, lane = tid & 63, e = tid >> 6;
  int running = 0;
  for (int c = 0; c < Tt; c += 256) {
    int m0 = idx[c + lane];
    int m1 = idx[c + 64 + lane];
    int m2 = idx[c + 128 + lane];
    int m3 = idx[c + 192 + lane];
#define RND(mv, base) { \
    unsigned long long mm = __ballot(mv == e); \
    int p = running + __popcll(mm & ((1ull << lane) - 1ull)); \
    if (mv == e) { pos[(base) + lane] = p; if (p < CAP) smap[e * CAP + p] = (base) + lane; } \
    running += (int)__popcll(mm); }
    RND(m0, c) RND(m1, c + 64) RND(m2, c + 128) RND(m3, c + 192)
#undef RND
  }
  __shared__ int scnt[8];
  __shared__ float smesum[8];
  __shared__ float red[512];
  if (lane == 0) scnt[e] = running;
  float part = 0.f;
  int ee = tid & 7, b0 = tid >> 3;
  for (int b = b0; b < nblkG; b += 64) part += meP[b * 8 + ee];
  red[tid] = part;
  __syncthreads();
  if (tid < 8) {
    float s = 0.f;
    for (int i = 0; i < 64; ++i) s += red[i * 8 + tid];
    smesum[tid] = s;
  }
  __syncthreads();
  if (tid == 0) {
    float l = 0.f;
    for (int q = 0; q < 8; ++q) l += smesum[q] * (float)scnt[q];
    laux_out[0] = l * 8.0f / ((float)Tt * (float)Tt);
  }
}

// ------------- zero dropped-token output rows -------------
__global__ __launch_bounds__(256) void zero_dropped(
    const int* __restrict__ pos, float* __restrict__ out) {
  int t = blockIdx.x;
  if (pos[t] < CAP) return;
  ((float4*)(out + (size_t)t * Dd))[threadIdx.x] = make_float4(0.f, 0.f, 0.f, 0.f);
}

// ------------- merged transpose + cast fp32 -> bf16 (both weights) ----------
__global__ __launch_bounds__(256) void transpose_cast2(
    const float* __restrict__ w1, const float* __restrict__ w2,
    unsigned short* __restrict__ W1T, unsigned short* __restrict__ W2T) {
  __shared__ float tile[64][65];
  int z = blockIdx.z, tz = blockIdx.x;
  const float* s; unsigned short* d; int R, Cn, rb, cb;
  if (z < 8) {
    s = w1 + (size_t)z * Dd * DFFf; d = W1T + (size_t)z * Dd * DFFf;
    R = Dd; Cn = DFFf; rb = (tz >> 6) * 64; cb = (tz & 63) * 64;
  } else {
    s = w2 + (size_t)(z - 8) * DFFf * Dd; d = W2T + (size_t)(z - 8) * DFFf * Dd;
    R = DFFf; Cn = Dd; rb = (tz >> 4) * 64; cb = (tz & 15) * 64;
  }
  int c = threadIdx.x & 63;
  int r0 = threadIdx.x >> 6;
#pragma unroll
  for (int i = 0; i < 16; ++i) {
    int r = r0 + i * 4;
    tile[r][c] = s[(size_t)(rb + r) * Cn + cb + c];
  }
  __syncthreads();
#pragma unroll
  for (int i = 0; i < 16; ++i) {
    int r = r0 + i * 4;
    d[(size_t)(cb + r) * R + rb + c] = f2bf(tile[c][r]);
  }
}

// ------------- gather + cast dispatched tokens -------------
__global__ __launch_bounds__(256) void build_xg(
    const float* __restrict__ x, const int* __restrict__ smap,
    unsigned short* __restrict__ Xg) {
  int row = blockIdx.x;
  int t = smap[row];
  int j = threadIdx.x;
  float4 v = make_float4(0.f, 0.f, 0.f, 0.f);
  if (t >= 0) v = ((const float4*)(x + (size_t)t * Dd))[j];
  ushort4 o;
  o.x = f2bf(v.x); o.y = f2bf(v.y); o.z = f2bf(v.z); o.w = f2bf(v.w);
  ((ushort4*)(Xg + (size_t)row * Dd))[j] = o;
}

// ------- 128x256-tile bf16 MFMA GEMM (B^T), BK=32, 3-slot ring, 2 blocks/CU --
// 512 thr = 8 waves (2M x 4N), per-wave 64x64 (acc 64 VGPR -> <=128 total ->
// 4 waves/SIMD -> 2 blocks/CU: cross-block TLP hides drains, m97/m114 mech).
// LDS slot = 24 KB {A 128x32 8K | B 256x32 16K}, 3 slots = 72 KB; stage t+2
// during t, vmcnt(3)/tile (2-tile HBM cover, never 0 until tail).
// Layout (r8-verified 0-conflict): rows 2l,2l+1 share a 128-B line,
// col = ((row&1)<<2) | (kg ^ ((row>>1)&3)); staging dest linear.
template <int DO_GELU, int FUSE_COMBINE>
__global__ __launch_bounds__(512, 4) void gemm3r_kernel(
    const unsigned short* __restrict__ A,   // [E][M][K] bf16
    const unsigned short* __restrict__ BT,  // [E][N][K] bf16
    unsigned short* __restrict__ Hout,      // [E][M][N] bf16 (GEMM1)
    const int* __restrict__ smap,           // [E][CAP] token map (GEMM2)
    const float* __restrict__ gate,         // [T]
    float* __restrict__ out,                // [T][D]
    int M, int N, int K) {
  __shared__ char lds[73728];  // 3 slots x 24576
  int tid = threadIdx.x, lane = tid & 63, w = tid >> 6;
  int wm = w >> 2, wn = w & 3;

  // bijective XCD-aware swizzle; bm fastest (consecutive blocks share B-panel)
  int gx = gridDim.x, gy = gridDim.y;
  long gid = blockIdx.x + (long)gx * (blockIdx.y + (long)gy * blockIdx.z);
  int nT = gx * gy * (int)gridDim.z;
  int cpx = nT >> 3;
  int swz = (int)((gid & 7) * (long)cpx + (gid >> 3));
  int bm = swz % gx;
  int bn = (swz / gx) % gy;
  int e  = swz / (gx * gy);

  const char* Ab = (const char*)(A + ((size_t)e * M + (size_t)bm * 128) * K);
  const char* Bb = (const char*)(BT + ((size_t)e * N + (size_t)bn * 256) * K);
  int K2 = K * 2;

  // staging source offsets (thread-const): region phys p -> (row, k-granule)
  unsigned sv0, sv1;
  {
    int p = tid * 16, ln = p >> 7, cl = (p >> 4) & 7;
    sv0 = (unsigned)((2 * ln + (cl >> 2)) * K2 + (((cl & 3) ^ (ln & 3)) << 4));
    p = 8192 + tid * 16; ln = p >> 7; cl = (p >> 4) & 7;
    sv1 = (unsigned)((2 * ln + (cl >> 2)) * K2 + (((cl & 3) ^ (ln & 3)) << 4));
  }
  const char* pA  = Ab + sv0;
  const char* pB0 = Bb + sv0;
  const char* pB1 = Bb + sv1;
  char* dstBase = (char*)lds + tid * 16;

  // fragment local offsets (slot-relative)
  int arow = wm * 64 + (lane & 15);
  int brow = wn * 64 + (lane & 15);
  unsigned kg = (unsigned)(lane >> 4);
  unsigned aLoc = (unsigned)((arow >> 1) * 128 +
                  ((((arow & 1) << 2) | (kg ^ ((unsigned)(arow >> 1) & 3u))) << 4));
  unsigned bLoc = 8192u + (unsigned)((brow >> 1) * 128 +
                  ((((brow & 1) << 2) | (kg ^ ((unsigned)(brow >> 1) & 3u))) << 4));
  unsigned lb = (unsigned)(size_t)(__attribute__((address_space(3))) char*)lds;
  unsigned rA = lb, rB = lb + 24576u, rC = lb + 49152u;

  f32x4 acc[4][4];
#pragma unroll
  for (int mi = 0; mi < 4; ++mi)
#pragma unroll
    for (int n = 0; n < 4; ++n) acc[mi][n] = (f32x4){0.f, 0.f, 0.f, 0.f};

#define STAGE3(DOFF) { \
    char* d_ = dstBase + (DOFF); \
    gld16(pA, d_); gld16(pB0, d_ + 8192); gld16(pB1, d_ + 16384); \
    pA += 64; pB0 += 64; pB1 += 64; }
#define SB0 __builtin_amdgcn_sched_barrier(0)

  int NT = K >> 5;  // BK = 32
  // prologue: stage tiles 0,1 into slots 0,1; drain tile 0
  STAGE3(0)
  STAGE3(24576)
  VMCNT(3);
  __builtin_amdgcn_s_barrier();

  for (int t = 0; t < NT; ++t) {
    bool pf = (t + 2 < NT);
    if (pf) STAGE3(rC - lb)            // stage t+2 into slot (t+2)%3
    unsigned au = rA + aLoc, bu = rA + bLoc;
    bf16x8 a0, a1, a2, a3, b0, b1, b2, b3;
    b0 = dsr<0>(bu); b1 = dsr<1024>(bu); b2 = dsr<2048>(bu); b3 = dsr<3072>(bu);
    a0 = dsr<0>(au); a1 = dsr<1024>(au); a2 = dsr<2048>(au); a3 = dsr<3072>(au);
    LGKM(2); SB0;
    __builtin_amdgcn_s_setprio(1);
#define MF(AV, MI_, BV, N_) acc[MI_][N_] = __builtin_amdgcn_mfma_f32_16x16x32_bf16(AV, BV, acc[MI_][N_], 0, 0, 0)
    MF(a0, 0, b0, 0); MF(a0, 0, b1, 1); MF(a0, 0, b2, 2); MF(a0, 0, b3, 3);
    MF(a1, 1, b0, 0); MF(a1, 1, b1, 1); MF(a1, 1, b2, 2); MF(a1, 1, b3, 3);
    __builtin_amdgcn_s_setprio(0);
    LGKM(0); SB0;
    __builtin_amdgcn_s_setprio(1);
    MF(a2, 2, b0, 0); MF(a2, 2, b1, 1); MF(a2, 2, b2, 2); MF(a2, 2, b3, 3);
    MF(a3, 3, b0, 0); MF(a3, 3, b1, 1); MF(a3, 3, b2, 2); MF(a3, 3, b3, 3);
    __builtin_amdgcn_s_setprio(0);
#undef MF
    if (pf) { VMCNT(3); } else { VMCNT(0); }
    __builtin_amdgcn_s_barrier();
    unsigned tr = rA; rA = rB; rB = rC; rC = tr;  // rotate ring
  }
#undef STAGE3
#undef SB0

  // ---- epilogue ----
  int r0 = bm * 128 + wm * 64;
  int c0 = bn * 256 + wn * 64;
#pragma unroll
  for (int mi = 0; mi < 4; ++mi) {
    int rowb = r0 + mi * 16 + ((lane >> 4) << 2);
#pragma unroll
    for (int r = 0; r < 4; ++r) {
      int row = rowb + r;
      if (DO_GELU) {
#pragma unroll
        for (int n = 0; n < 4; ++n) {
          int col = c0 + n * 16 + (lane & 15);
          Hout[((size_t)e * M + row) * N + col] = f2bf(gelu_tanh(acc[mi][n][r]));
        }
      }
      if (FUSE_COMBINE) {
        int tkn = smap[e * CAP + row];
        if (tkn >= 0) {
          float gt = gate[tkn];
#pragma unroll
          for (int n = 0; n < 4; ++n) {
            int col = c0 + n * 16 + (lane & 15);
            out[(size_t)tkn * Dd + col] = acc[mi][n][r] * gt;
          }
        }
      }
    }
  }
}

extern "C" void kernel_launch(void* const* d_in, const int* in_sizes, int n_in,
                              void* d_out, int out_size, void* d_ws, size_t ws_size,
                              hipStream_t stream) {
  const float* x  = (const float*)d_in[0];
  const float* wg = (const float*)d_in[1];
  const float* w1 = (const float*)d_in[2];
  const float* w2 = (const float*)d_in[3];
  float* out = (float*)d_out;

  char* ws = (char*)d_ws;
  int*   idx  = (int*)(ws + 0);
  int*   pos  = (int*)(ws + 65536);
  float* gate = (float*)(ws + 131072);
  float* meP  = (float*)(ws + 196608);
  int*   smap = (int*)(ws + 327680);
  unsigned short* Xg  = (unsigned short*)(ws + 393216ull);
  unsigned short* W1T = (unsigned short*)(ws + 33947648ull);
  unsigned short* W2T = (unsigned short*)(ws + 101056512ull);
  unsigned short* H   = (unsigned short*)(ws + 168165376ull);

  hipMemsetAsync(smap, 0xFF, Ee * CAP * 4, stream);
  gating_kernel<<<Tt / 4, 256, 0, stream>>>(x, wg, idx, gate, meP);
  scan_kernel<<<1, 512, 0, stream>>>(idx, pos, smap, meP, Tt / 4,
                                     out + (size_t)Tt * Dd);
  zero_dropped<<<Tt, 256, 0, stream>>>(pos, out);
  transpose_cast2<<<dim3(1024, 1, 16), 256, 0, stream>>>(w1, w2, W1T, W2T);
  build_xg<<<Ee * CAP, 256, 0, stream>>>(x, smap, Xg);
  gemm3r_kernel<1, 0><<<dim3(CAP / 128, DFFf / 256, Ee), 512, 0, stream>>>(
      Xg, W1T, H, nullptr, nullptr, nullptr, CAP, DFFf, Dd);
  gemm3r_kernel<0, 1><<<dim3(CAP / 128, Dd / 256, Ee), 512, 0, stream>>>(
      H, W2T, nullptr, smap, gate, out, CAP, Dd, DFFf);
}

// Round 10
// 510.140 us; speedup vs baseline: 1.0494x; 1.0494x over previous
//
#include <hip/hip_runtime.h>
#include <hip/hip_bf16.h>

#define Tt   16384
#define Dd   1024
#define Ee   8
#define CAP  2048
#define DFFf 4096

typedef __attribute__((ext_vector_type(8))) short bf16x8;
typedef __attribute__((ext_vector_type(4))) float f32x4;

__device__ __forceinline__ unsigned short f2bf(float f) {
  union { float f; unsigned u; } v; v.f = f;
  unsigned r = (v.u + 0x7FFFu + ((v.u >> 16) & 1u)) >> 16;
  return (unsigned short)r;
}

__device__ __forceinline__ float gelu_tanh(float x) {
  float z = 0.7978845608028654f * (x + 0.044715f * x * x * x);
  float az = fabsf(z);
  float t = __expf(-2.0f * az);
  float th = (1.0f - t) / (1.0f + t);
  th = (z < 0.0f) ? -th : th;
  return 0.5f * x * (1.0f + th);
}

__device__ __forceinline__ void gld16(const void* g, void* l) {
  __builtin_amdgcn_global_load_lds(
      (const __attribute__((address_space(1))) void*)g,
      (__attribute__((address_space(3))) void*)l,
      16, 0, 0);
}

template <int IMM>
__device__ __forceinline__ bf16x8 dsr(unsigned a) {
  bf16x8 r;
  asm volatile("ds_read_b128 %0, %1 offset:%c2" : "=v"(r) : "v"(a), "i"(IMM));
  return r;
}
#define LGKM(N) asm volatile("s_waitcnt lgkmcnt(" #N ")" ::: "memory")
#define VMCNT(N) asm volatile("s_waitcnt vmcnt(" #N ")" ::: "memory")

// ---------------- gating: logits fp32, softmax, argmax ----------------
__global__ __launch_bounds__(256) void gating_kernel(
    const float* __restrict__ x, const float* __restrict__ wg,
    int* __restrict__ idx, float* __restrict__ gate, float* __restrict__ meP) {
  int tid = threadIdx.x, lane = tid & 63, w = tid >> 6;
  int t = blockIdx.x * 4 + w;
  const float* xr = x + (size_t)t * Dd;
  float p[8];
#pragma unroll
  for (int e2 = 0; e2 < 8; ++e2) p[e2] = 0.f;
#pragma unroll
  for (int i = 0; i < 16; ++i) {
    int j = lane + (i << 6);
    float xv = xr[j];
    const float4* wr = (const float4*)(wg + j * 8);
    float4 a = wr[0], b = wr[1];
    p[0] += xv * a.x; p[1] += xv * a.y; p[2] += xv * a.z; p[3] += xv * a.w;
    p[4] += xv * b.x; p[5] += xv * b.y; p[6] += xv * b.z; p[7] += xv * b.w;
  }
#pragma unroll
  for (int off = 32; off > 0; off >>= 1)
#pragma unroll
    for (int e2 = 0; e2 < 8; ++e2) p[e2] += __shfl_xor(p[e2], off);
  __shared__ float smG[4][8];
  if (lane == 0) {
    float mx = p[0]; int am = 0;
#pragma unroll
    for (int e2 = 1; e2 < 8; ++e2) if (p[e2] > mx) { mx = p[e2]; am = e2; }
    float s = 0.f, g2[8];
#pragma unroll
    for (int e2 = 0; e2 < 8; ++e2) { g2[e2] = __expf(p[e2] - mx); s += g2[e2]; }
    float inv = 1.f / s;
    idx[t] = am;
    gate[t] = g2[am] * inv;
#pragma unroll
    for (int e2 = 0; e2 < 8; ++e2) smG[w][e2] = g2[e2] * inv;
  }
  __syncthreads();
  if (tid < 8)
    meP[blockIdx.x * 8 + tid] = smG[0][tid] + smG[1][tid] + smG[2][tid] + smG[3][tid];
}

// ------------- scan: per-expert cumulative position + l_aux -------------
__global__ __launch_bounds__(512) void scan_kernel(
    const int* __restrict__ idx, int* __restrict__ pos, int* __restrict__ smap,
    const float* __restrict__ meP, int nblkG, float* __restrict__ laux_out) {
  int tid = threadIdx.x, lane = tid & 63, e = tid >> 6;
  int running = 0;
  for (int c = 0; c < Tt; c += 256) {
    int m0 = idx[c + lane];
    int m1 = idx[c + 64 + lane];
    int m2 = idx[c + 128 + lane];
    int m3 = idx[c + 192 + lane];
#define RND(mv, base) { \
    unsigned long long mm = __ballot(mv == e); \
    int p = running + __popcll(mm & ((1ull << lane) - 1ull)); \
    if (mv == e) { pos[(base) + lane] = p; if (p < CAP) smap[e * CAP + p] = (base) + lane; } \
    running += (int)__popcll(mm); }
    RND(m0, c) RND(m1, c + 64) RND(m2, c + 128) RND(m3, c + 192)
#undef RND
  }
  __shared__ int scnt[8];
  __shared__ float smesum[8];
  __shared__ float red[512];
  if (lane == 0) scnt[e] = running;
  float part = 0.f;
  int ee = tid & 7, b0 = tid >> 3;
  for (int b = b0; b < nblkG; b += 64) part += meP[b * 8 + ee];
  red[tid] = part;
  __syncthreads();
  if (tid < 8) {
    float s = 0.f;
    for (int i = 0; i < 64; ++i) s += red[i * 8 + tid];
    smesum[tid] = s;
  }
  __syncthreads();
  if (tid == 0) {
    float l = 0.f;
    for (int q = 0; q < 8; ++q) l += smesum[q] * (float)scnt[q];
    laux_out[0] = l * 8.0f / ((float)Tt * (float)Tt);
  }
}

// ------------- zero dropped-token output rows -------------
__global__ __launch_bounds__(256) void zero_dropped(
    const int* __restrict__ pos, float* __restrict__ out) {
  int t = blockIdx.x;
  if (pos[t] < CAP) return;
  ((float4*)(out + (size_t)t * Dd))[threadIdx.x] = make_float4(0.f, 0.f, 0.f, 0.f);
}

// ------------- merged transpose + cast fp32 -> bf16 (both weights) ----------
__global__ __launch_bounds__(256) void transpose_cast2(
    const float* __restrict__ w1, const float* __restrict__ w2,
    unsigned short* __restrict__ W1T, unsigned short* __restrict__ W2T) {
  __shared__ float tile[64][65];
  int z = blockIdx.z, tz = blockIdx.x;
  const float* s; unsigned short* d; int R, Cn, rb, cb;
  if (z < 8) {
    s = w1 + (size_t)z * Dd * DFFf; d = W1T + (size_t)z * Dd * DFFf;
    R = Dd; Cn = DFFf; rb = (tz >> 6) * 64; cb = (tz & 63) * 64;
  } else {
    s = w2 + (size_t)(z - 8) * DFFf * Dd; d = W2T + (size_t)(z - 8) * DFFf * Dd;
    R = DFFf; Cn = Dd; rb = (tz >> 4) * 64; cb = (tz & 15) * 64;
  }
  int c = threadIdx.x & 63;
  int r0 = threadIdx.x >> 6;
#pragma unroll
  for (int i = 0; i < 16; ++i) {
    int r = r0 + i * 4;
    tile[r][c] = s[(size_t)(rb + r) * Cn + cb + c];
  }
  __syncthreads();
#pragma unroll
  for (int i = 0; i < 16; ++i) {
    int r = r0 + i * 4;
    d[(size_t)(cb + r) * R + rb + c] = f2bf(tile[c][r]);
  }
}

// ------------- gather + cast dispatched tokens -------------
__global__ __launch_bounds__(256) void build_xg(
    const float* __restrict__ x, const int* __restrict__ smap,
    unsigned short* __restrict__ Xg) {
  int row = blockIdx.x;
  int t = smap[row];
  int j = threadIdx.x;
  float4 v = make_float4(0.f, 0.f, 0.f, 0.f);
  if (t >= 0) v = ((const float4*)(x + (size_t)t * Dd))[j];
  ushort4 o;
  o.x = f2bf(v.x); o.y = f2bf(v.y); o.z = f2bf(v.z); o.w = f2bf(v.w);
  ((ushort4*)(Xg + (size_t)row * Dd))[j] = o;
}

// ------ 256^2-tile bf16 MFMA GEMM (B^T), BK=32, 3-slot ring, 1 barrier/tile --
// 512 thr = 8 waves (2M x 4N), per-wave 128x64 (good perimeter/area; r9 lesson).
// LDS: 3 slots x 32 KB {A 256x32 16K | B 16K} = 96 KB. Stage t+2 during t;
// vmcnt(4) per tile (2-tile cover, never 0 until tail); ONE barrier per tile so
// waves desync across the tile body: LDS-read stream overlaps MFMA bursts.
// Counted lgkm(4)/(0) between the two 16-MFMA clusters.
// Layout (r8-verified 0-conflict): rows 2l,2l+1 share a 128-B line,
// col = ((row&1)<<2) | (kg ^ ((row>>1)&3)); staging dest linear.
template <int DO_GELU, int FUSE_COMBINE>
__global__ __launch_bounds__(512, 2) void gemmr3_kernel(
    const unsigned short* __restrict__ A,   // [E][M][K] bf16
    const unsigned short* __restrict__ BT,  // [E][N][K] bf16
    unsigned short* __restrict__ Hout,      // [E][M][N] bf16 (GEMM1)
    const int* __restrict__ smap,           // [E][CAP] token map (GEMM2)
    const float* __restrict__ gate,         // [T]
    float* __restrict__ out,                // [T][D]
    int M, int N, int K) {
  __shared__ char lds[98304];  // 3 slots x 32768
  int tid = threadIdx.x, lane = tid & 63, w = tid >> 6;
  int wm = w >> 2, wn = w & 3;

  // bijective XCD-aware swizzle (nwg % 8 == 0)
  int gx = gridDim.x, gy = gridDim.y;
  long gid = blockIdx.x + (long)gx * (blockIdx.y + (long)gy * blockIdx.z);
  int nT = gx * gy * (int)gridDim.z;
  int cpx = nT >> 3;
  int swz = (int)((gid & 7) * (long)cpx + (gid >> 3));
  int bn = swz % gx;
  int bm = (swz / gx) % gy;
  int e  = swz / (gx * gy);

  const char* Ab = (const char*)(A + ((size_t)e * M + (size_t)bm * 256) * K);
  const char* Bb = (const char*)(BT + ((size_t)e * N + (size_t)bn * 256) * K);
  int K2 = K * 2;

  // staging source offsets (thread-const): region phys p -> (row, k-granule)
  unsigned sv0, sv1;
  {
    int p = tid * 16, ln = p >> 7, cl = (p >> 4) & 7;
    sv0 = (unsigned)((2 * ln + (cl >> 2)) * K2 + (((cl & 3) ^ (ln & 3)) << 4));
    p = 8192 + tid * 16; ln = p >> 7; cl = (p >> 4) & 7;
    sv1 = (unsigned)((2 * ln + (cl >> 2)) * K2 + (((cl & 3) ^ (ln & 3)) << 4));
  }
  const char* pA0 = Ab + sv0;
  const char* pA1 = Ab + sv1;
  const char* pB0 = Bb + sv0;
  const char* pB1 = Bb + sv1;
  char* dstBase = (char*)lds + tid * 16;

  // fragment local offsets (slot-relative); +16 rows => +1024 B
  int arow = wm * 128 + (lane & 15);
  int brow = wn * 64 + (lane & 15);
  unsigned kg = (unsigned)(lane >> 4);
  unsigned aLoc = (unsigned)((arow >> 1) * 128 +
                  ((((arow & 1) << 2) | (kg ^ ((unsigned)(arow >> 1) & 3u))) << 4));
  unsigned bLoc = 16384u + (unsigned)((brow >> 1) * 128 +
                  ((((brow & 1) << 2) | (kg ^ ((unsigned)(brow >> 1) & 3u))) << 4));
  unsigned lb = (unsigned)(size_t)(__attribute__((address_space(3))) char*)lds;
  unsigned rA = lb, rB = lb + 32768u, rC = lb + 65536u;

  f32x4 acc[2][4][4];
#pragma unroll
  for (int mh = 0; mh < 2; ++mh)
#pragma unroll
    for (int mi = 0; mi < 4; ++mi)
#pragma unroll
      for (int n = 0; n < 4; ++n) acc[mh][mi][n] = (f32x4){0.f, 0.f, 0.f, 0.f};

#define STAGE4(DOFF) { \
    char* d_ = dstBase + (DOFF); \
    gld16(pA0, d_); gld16(pA1, d_ + 8192); \
    gld16(pB0, d_ + 16384); gld16(pB1, d_ + 24576); \
    pA0 += 64; pA1 += 64; pB0 += 64; pB1 += 64; }
#define SB0 __builtin_amdgcn_sched_barrier(0)

  int NT = K >> 5;  // BK = 32
  // prologue: stage tiles 0,1 into slots 0,1; drain tile 0
  STAGE4(0)
  STAGE4(32768)
  VMCNT(4);
  __builtin_amdgcn_s_barrier();

  for (int t = 0; t < NT; ++t) {
    bool pf = (t + 2 < NT);
    if (pf) STAGE4(rC - lb)            // stage t+2 into slot (t+2)%3
    unsigned au = rA + aLoc, bu = rA + bLoc;
    bf16x8 b0, b1, b2, b3, a0, a1, a2, a3, a4, a5, a6, a7;
    b0 = dsr<0>(bu); b1 = dsr<1024>(bu); b2 = dsr<2048>(bu); b3 = dsr<3072>(bu);
    a0 = dsr<0>(au); a1 = dsr<1024>(au); a2 = dsr<2048>(au); a3 = dsr<3072>(au);
    a4 = dsr<4096>(au); a5 = dsr<5120>(au); a6 = dsr<6144>(au); a7 = dsr<7168>(au);
    LGKM(4); SB0;
    __builtin_amdgcn_s_setprio(1);
#define MF(AV, MH_, MI_, BV, N_) acc[MH_][MI_][N_] = \
    __builtin_amdgcn_mfma_f32_16x16x32_bf16(AV, BV, acc[MH_][MI_][N_], 0, 0, 0)
    MF(a0, 0, 0, b0, 0); MF(a0, 0, 0, b1, 1); MF(a0, 0, 0, b2, 2); MF(a0, 0, 0, b3, 3);
    MF(a1, 0, 1, b0, 0); MF(a1, 0, 1, b1, 1); MF(a1, 0, 1, b2, 2); MF(a1, 0, 1, b3, 3);
    MF(a2, 0, 2, b0, 0); MF(a2, 0, 2, b1, 1); MF(a2, 0, 2, b2, 2); MF(a2, 0, 2, b3, 3);
    MF(a3, 0, 3, b0, 0); MF(a3, 0, 3, b1, 1); MF(a3, 0, 3, b2, 2); MF(a3, 0, 3, b3, 3);
    __builtin_amdgcn_s_setprio(0);
    LGKM(0); SB0;
    __builtin_amdgcn_s_setprio(1);
    MF(a4, 1, 0, b0, 0); MF(a4, 1, 0, b1, 1); MF(a4, 1, 0, b2, 2); MF(a4, 1, 0, b3, 3);
    MF(a5, 1, 1, b0, 0); MF(a5, 1, 1, b1, 1); MF(a5, 1, 1, b2, 2); MF(a5, 1, 1, b3, 3);
    MF(a6, 1, 2, b0, 0); MF(a6, 1, 2, b1, 1); MF(a6, 1, 2, b2, 2); MF(a6, 1, 2, b3, 3);
    MF(a7, 1, 3, b0, 0); MF(a7, 1, 3, b1, 1); MF(a7, 1, 3, b2, 2); MF(a7, 1, 3, b3, 3);
    __builtin_amdgcn_s_setprio(0);
#undef MF
    if (t + 1 < NT) {
      if (pf) { VMCNT(4); } else { VMCNT(0); }
      __builtin_amdgcn_s_barrier();
      unsigned tr = rA; rA = rB; rB = rC; rC = tr;  // rotate ring
    }
  }
#undef STAGE4
#undef SB0

  // ---- epilogue ----
  int r0 = bm * 256 + wm * 128;
  int c0 = bn * 256 + wn * 64;
#pragma unroll
  for (int mh = 0; mh < 2; ++mh)
#pragma unroll
    for (int mi = 0; mi < 4; ++mi) {
      int rowb = r0 + mh * 64 + mi * 16 + ((lane >> 4) << 2);
#pragma unroll
      for (int r = 0; r < 4; ++r) {
        int row = rowb + r;
        if (DO_GELU) {
#pragma unroll
          for (int n = 0; n < 4; ++n) {
            int col = c0 + n * 16 + (lane & 15);
            Hout[((size_t)e * M + row) * N + col] = f2bf(gelu_tanh(acc[mh][mi][n][r]));
          }
        }
        if (FUSE_COMBINE) {
          int tkn = smap[e * CAP + row];
          if (tkn >= 0) {
            float gt = gate[tkn];
#pragma unroll
            for (int n = 0; n < 4; ++n) {
              int col = c0 + n * 16 + (lane & 15);
              out[(size_t)tkn * Dd + col] = acc[mh][mi][n][r] * gt;
            }
          }
        }
      }
    }
}

extern "C" void kernel_launch(void* const* d_in, const int* in_sizes, int n_in,
                              void* d_out, int out_size, void* d_ws, size_t ws_size,
                              hipStream_t stream) {
  const float* x  = (const float*)d_in[0];
  const float* wg = (const float*)d_in[1];
  const float* w1 = (const float*)d_in[2];
  const float* w2 = (const float*)d_in[3];
  float* out = (float*)d_out;

  char* ws = (char*)d_ws;
  int*   idx  = (int*)(ws + 0);
  int*   pos  = (int*)(ws + 65536);
  float* gate = (float*)(ws + 131072);
  float* meP  = (float*)(ws + 196608);
  int*   smap = (int*)(ws + 327680);
  unsigned short* Xg  = (unsigned short*)(ws + 393216ull);
  unsigned short* W1T = (unsigned short*)(ws + 33947648ull);
  unsigned short* W2T = (unsigned short*)(ws + 101056512ull);
  unsigned short* H   = (unsigned short*)(ws + 168165376ull);

  hipMemsetAsync(smap, 0xFF, Ee * CAP * 4, stream);
  gating_kernel<<<Tt / 4, 256, 0, stream>>>(x, wg, idx, gate, meP);
  scan_kernel<<<1, 512, 0, stream>>>(idx, pos, smap, meP, Tt / 4,
                                     out + (size_t)Tt * Dd);
  zero_dropped<<<Tt, 256, 0, stream>>>(pos, out);
  transpose_cast2<<<dim3(1024, 1, 16), 256, 0, stream>>>(w1, w2, W1T, W2T);
  build_xg<<<Ee * CAP, 256, 0, stream>>>(x, smap, Xg);
  gemmr3_kernel<1, 0><<<dim3(DFFf / 256, CAP / 256, Ee), 512, 0, stream>>>(
      Xg, W1T, H, nullptr, nullptr, nullptr, CAP, DFFf, Dd);
  gemmr3_kernel<0, 1><<<dim3(Dd / 256, CAP / 256, Ee), 512, 0, stream>>>(
      H, W2T, nullptr, smap, gate, out, CAP, Dd, DFFf);
}